// Round 6
// baseline (130.915 us; speedup 1.0000x reference)
//
#include <hip/hip_runtime.h>

// Problem constants (fixed by the reference).
#define N_SPK 1024
#define M_UTT 32
#define D_EMB 512
#define NROWS (N_SPK * M_UTT)   // 32768

#define NEG_INF (-__builtin_inff())
#define MARGIN 25.0f   // skip row iff dgl - rowbound >= MARGIN (err < 1.4e-8/row)

using f32x4 = __attribute__((ext_vector_type(4))) float;

// ===========================================================================
// FAST PATH (round 16): prune-then-compute, 2 dispatches (was 3).
//
// R15 post-mortem: block-count scaling law confirmed again (active 15->~6us
// at 4x blocks).  Remaining controllable pieces: prep (~13us, near its 67MB
// HBM floor), select (~2.5us), active (~6us).  R16 folds select INTO the
// active kernel:
//   Phase A: each block max-reduces c2A (4KB, L2-hot) -> Cmax.  fmaxf is
//     rounding-free so ANY reduction order gives bit-identical Cmax.
//   Phase B: block (strip=blockIdx>>4 of 512 rows, g16=blockIdx&15) scans
//     its strip with the IDENTICAL predicate (same fma/sqrt ops), __ballot
//     enumerates survivors in row order; for each survivor the block
//     computes its g16 partial exactly as R15 (identical butterfly) and
//     release-stores pm16[row*16+g16]; the g16==0 block appends the row to
//     active[] (agent-scope atomics -- XCD L2s are not cross-coherent).
//   Phase C: per-BLOCK done counter (1024 adds of 1; finisher = old==1023,
//     trivially unique and count is final by acq_rel ordering) merges all
//     slots with the identical old nesting -> bit-exact, absmax 0.0.
//
// Merge-order note: out accumulation order is nondeterministic, but loss is
// dominated by ~1 extreme row; other survivors contribute exactly 0.0 and
// 0.0 + x == x bit-exactly, so the sum is order-robust (observed absmax 0.0
// across R10-R15).
//
// Math unchanged from R10: dgl ~ 2641 +- 630 while every off-diag logit is
// bounded by |w|*||e||*max||c|| + b ~ 459 (Cauchy-Schwarz).  Rows with
// dgl - bound >= 25 nats contribute exactly-0 loss in the reference too.
// R11 kept: no init dispatch (prep block 0 zeroes out/count/blocksDone).
// ===========================================================================

// ---------------------------------------------------------------------------
// prep: one block per speaker n (32 rows x 512 dims).  Reads e ONCE.
//  - sumf[n*512+d] = sum_m e[n][m][d]      (fp32 speaker sum, 2 MB)
//  - ssqA[row]     = ||e_row||^2
//  - dgl[row]      = w*(e.sum + ||e||^2/31) + b   (exact fp32 diag logit)
//  - c2A[n]        = ||c_n||^2             (per-speaker, no atomics)
//  - block 0 zeroes out[0], *count, *blocksDone (replaces init dispatch)
// ---------------------------------------------------------------------------
__global__ __launch_bounds__(256)
void prep_kernel(const float* __restrict__ e,
                 float* __restrict__ sumf, float* __restrict__ ssqA,
                 float* __restrict__ dgl, float* __restrict__ c2A,
                 const float* __restrict__ wp, const float* __restrict__ bp,
                 float* __restrict__ out, int* __restrict__ count,
                 int* __restrict__ blocksDone) {
    __shared__ float csum[4][D_EMB];   // 8 KiB
    __shared__ float c2red[4];
    const int n = blockIdx.x;
    const int wv = threadIdx.x >> 6, l = threadIdx.x & 63;

    if (n == 0 && threadIdx.x == 0) { out[0] = 0.f; *count = 0; *blocksDone = 0; }

    float xs[8][8];     // retained row data (lane's 8 dims x 8 rows)
    float ssq[8];       // per-row ||e||^2 (wave-uniform after butterfly)
    float cacc[8];
#pragma unroll
    for (int j = 0; j < 8; ++j) cacc[j] = 0.f;

#pragma unroll
    for (int mi = 0; mi < 8; ++mi) {
        const int m = mi * 4 + wv;
        const size_t row = (size_t)n * M_UTT + m;
        const float* p = e + row * D_EMB + l * 8;
        float4 x0 = *(const float4*)p;
        float4 x1 = *(const float4*)(p + 4);
        xs[mi][0] = x0.x; xs[mi][1] = x0.y; xs[mi][2] = x0.z; xs[mi][3] = x0.w;
        xs[mi][4] = x1.x; xs[mi][5] = x1.y; xs[mi][6] = x1.z; xs[mi][7] = x1.w;
        float sq = 0.f;
#pragma unroll
        for (int j = 0; j < 8; ++j) {
            float x = xs[mi][j];
            cacc[j] += x;
            sq = __builtin_fmaf(x, x, sq);
        }
#pragma unroll
        for (int off = 32; off; off >>= 1) sq += __shfl_xor(sq, off);
        ssq[mi] = sq;
        if (l == 0) ssqA[row] = sq;
    }

#pragma unroll
    for (int j = 0; j < 8; ++j) csum[wv][l * 8 + j] = cacc[j];
    __syncthreads();
    float c2acc = 0.f;
    for (int d = threadIdx.x; d < D_EMB; d += 256) {
        float s = csum[0][d] + csum[1][d] + csum[2][d] + csum[3][d];
        csum[0][d] = s;                               // full speaker sum
        sumf[(size_t)n * D_EMB + d] = s;
        float c = s * (1.0f / M_UTT);
        c2acc = __builtin_fmaf(c, c, c2acc);
    }
#pragma unroll
    for (int off = 32; off; off >>= 1) c2acc += __shfl_xor(c2acc, off);
    if (l == 0) c2red[wv] = c2acc;
    __syncthreads();   // csum[0] full sums + c2red visible
    if (threadIdx.x == 0)
        c2A[n] = (c2red[0] + c2red[1]) + (c2red[2] + c2red[3]);

    // Exact fp32 diag: dgl[row] = w*(e.sum + ssq/31) + b.
    float sv[8];
#pragma unroll
    for (int j = 0; j < 8; ++j) sv[j] = csum[0][l * 8 + j];
    const float w = wp[0], bb = bp[0];
#pragma unroll
    for (int mi = 0; mi < 8; ++mi) {
        float dg = 0.f;
#pragma unroll
        for (int j = 0; j < 8; ++j) dg = __builtin_fmaf(xs[mi][j], sv[j], dg);
#pragma unroll
        for (int off = 32; off; off >>= 1) dg += __shfl_xor(dg, off);
        if (l == 0) {
            const size_t row = (size_t)n * M_UTT + mi * 4 + wv;
            dgl[row] = __builtin_fmaf(w, dg + ssq[mi] * (1.0f / 31.0f), bb);
        }
    }
}

// ---------------------------------------------------------------------------
// act2: select + active + merge in ONE kernel.  1024 blocks x 64 threads.
//   strip = blockIdx>>4 (512 rows), g16 = blockIdx&15 (64-speaker group).
// See header comment for the three phases and the bit-exactness argument.
// ---------------------------------------------------------------------------
__global__ __launch_bounds__(64)
void act2_kernel(const float* __restrict__ e, const float* __restrict__ sumf,
                 const float* __restrict__ ssqA, const float* __restrict__ dgl,
                 const float* __restrict__ c2A,
                 const float* __restrict__ wp, const float* __restrict__ bp,
                 int* __restrict__ count, int* __restrict__ active,
                 float2* __restrict__ pm16, int* __restrict__ blocksDone,
                 float* __restrict__ out) {
    __shared__ float er[D_EMB];
    __shared__ int lastFlag;
    const int tid = threadIdx.x;              // 0..63
    const int g16 = blockIdx.x & 15;
    const int r0 = (blockIdx.x >> 4) * 512;   // strip base row
    const float w = wp[0], bb = bp[0];

    // --- Phase A: Cmax (bit-identical to old select's reduce) ------------
    float m = 0.f;   // c2 > 0 always
#pragma unroll
    for (int i = 0; i < 16; ++i) m = fmaxf(m, c2A[tid + i * 64]);
#pragma unroll
    for (int off = 32; off; off >>= 1) m = fmaxf(m, __shfl_xor(m, off));
    const float Cmax = __builtin_sqrtf(m);
    const float aw = __builtin_fabsf(w);

    // --- Phase B: scan strip; per survivor compute this block's partial --
    for (int i = 0; i < 8; ++i) {
        const int row = r0 + i * 64 + tid;
        const float bound = __builtin_fmaf(
            aw * __builtin_sqrtf(ssqA[row]), Cmax, bb);
        unsigned long long mask = __ballot(dgl[row] - bound < MARGIN);
        while (mask) {
            const int bit = __builtin_ctzll(mask);
            mask &= mask - 1;
            const int srow = r0 + i * 64 + bit;

            // stage e_row into LDS (one wave: in-order DS ops, barriers are
            // ~free s_barrier; kept for clarity)
            {
                const float4* src = (const float4*)(e + (size_t)srow * D_EMB);
                ((float4*)er)[tid * 2]     = src[tid * 2];
                ((float4*)er)[tid * 2 + 1] = src[tid * 2 + 1];
            }
            __syncthreads();

            const int j = g16 * 64 + tid;     // speaker (column) index
            const float* sp = sumf + (size_t)j * D_EMB;
            float d0 = 0.f, d1 = 0.f, d2 = 0.f, d3 = 0.f;
            for (int k = 0; k < D_EMB; k += 4) {
                float4 s4 = *(const float4*)(sp + k);
                d0 = __builtin_fmaf(er[k + 0], s4.x, d0);
                d1 = __builtin_fmaf(er[k + 1], s4.y, d1);
                d2 = __builtin_fmaf(er[k + 2], s4.z, d2);
                d3 = __builtin_fmaf(er[k + 3], s4.w, d3);
            }
            const float dot = (d0 + d1) + (d2 + d3);
            float lg = __builtin_fmaf(w, dot * (1.0f / M_UTT), bb);
            if (j == (srow >> 5)) lg = dgl[srow];   // exact diag substitution

            float mx = lg;
#pragma unroll
            for (int off = 32; off; off >>= 1)
                mx = fmaxf(mx, __shfl_xor(mx, off));
            float ss = __expf(lg - mx);
#pragma unroll
            for (int off = 32; off; off >>= 1) ss += __shfl_xor(ss, off);

            if (tid == 0) {
                float2 v; v.x = mx; v.y = ss;
                __hip_atomic_store(
                    (unsigned long long*)&pm16[(size_t)srow * 16 + g16],
                    __builtin_bit_cast(unsigned long long, v),
                    __ATOMIC_RELAXED, __HIP_MEMORY_SCOPE_AGENT);
                if (g16 == 0) {
                    int slot = atomicAdd(count, 1);   // device-scope
                    __hip_atomic_store(&active[slot], srow,
                                       __ATOMIC_RELAXED,
                                       __HIP_MEMORY_SCOPE_AGENT);
                }
            }
            __syncthreads();   // er reuse by next survivor
        }
    }

    // --- Phase C: block done-counter; unique finisher merges -------------
    if (tid == 0) {
        int old = __hip_atomic_fetch_add(blocksDone, 1, __ATOMIC_ACQ_REL,
                                         __HIP_MEMORY_SCOPE_AGENT);
        lastFlag = (old == (int)(gridDim.x) - 1);
    }
    __syncthreads();

    if (lastFlag) {
        const int cnt = __hip_atomic_load(count, __ATOMIC_RELAXED,
                                          __HIP_MEMORY_SCOPE_AGENT);
        // Merge ALL slots with the identical old nesting:
        //   per chunk c: combine groups 4c..4c+3, then the 4-chunk combine.
        for (int slot = tid; slot < cnt; slot += 64) {
            const int row = __hip_atomic_load(&active[slot], __ATOMIC_RELAXED,
                                              __HIP_MEMORY_SCOPE_AGENT);
            float2 pm[4];
#pragma unroll
            for (int c = 0; c < 4; ++c) {
                unsigned long long b0 = __hip_atomic_load(
                    (unsigned long long*)&pm16[(size_t)row * 16 + 4 * c + 0],
                    __ATOMIC_RELAXED, __HIP_MEMORY_SCOPE_AGENT);
                unsigned long long b1 = __hip_atomic_load(
                    (unsigned long long*)&pm16[(size_t)row * 16 + 4 * c + 1],
                    __ATOMIC_RELAXED, __HIP_MEMORY_SCOPE_AGENT);
                unsigned long long b2 = __hip_atomic_load(
                    (unsigned long long*)&pm16[(size_t)row * 16 + 4 * c + 2],
                    __ATOMIC_RELAXED, __HIP_MEMORY_SCOPE_AGENT);
                unsigned long long b3 = __hip_atomic_load(
                    (unsigned long long*)&pm16[(size_t)row * 16 + 4 * c + 3],
                    __ATOMIC_RELAXED, __HIP_MEMORY_SCOPE_AGENT);
                float2 r0v = __builtin_bit_cast(float2, b0);
                float2 r1v = __builtin_bit_cast(float2, b1);
                float2 r2v = __builtin_bit_cast(float2, b2);
                float2 r3v = __builtin_bit_cast(float2, b3);
                float M = fmaxf(fmaxf(r0v.x, r1v.x), fmaxf(r2v.x, r3v.x));
                float S = r0v.y * __expf(r0v.x - M)
                        + r1v.y * __expf(r1v.x - M)
                        + r2v.y * __expf(r2v.x - M)
                        + r3v.y * __expf(r3v.x - M);
                pm[c].x = M; pm[c].y = S;
            }
            float M = fmaxf(fmaxf(pm[0].x, pm[1].x), fmaxf(pm[2].x, pm[3].x));
            float S = pm[0].y * __expf(pm[0].x - M) + pm[1].y * __expf(pm[1].x - M)
                    + pm[2].y * __expf(pm[2].x - M) + pm[3].y * __expf(pm[3].x - M);
            float loss = M + __logf(S) - dgl[row];
            atomicAdd(out, loss * (1.0f / NROWS));
        }
    }
}

// ===========================================================================
// FALLBACK PATH (round-1 fp32 vector kernels) — used if ws_size is too small.
// ===========================================================================

__global__ void centroid_kernel(const float* __restrict__ e,
                                float* __restrict__ cent) {
    int gid = blockIdx.x * 256 + threadIdx.x;
    int n = gid >> 9;
    int d = gid & 511;
    const float* p = e + ((size_t)n * M_UTT) * D_EMB + d;
    float s = 0.f;
#pragma unroll
    for (int m = 0; m < M_UTT; ++m) s += p[(size_t)m * D_EMB];
    cent[gid] = s * (1.0f / M_UTT);
}

__global__ void normsq_kernel(const float* __restrict__ e,
                              float* __restrict__ nsq) {
    int wv = threadIdx.x >> 6;
    int lane = threadIdx.x & 63;
    int row = blockIdx.x * 4 + wv;
    const float* p = e + (size_t)row * D_EMB + lane;
    float s = 0.f;
#pragma unroll
    for (int j = 0; j < 8; ++j) { float x = p[j * 64]; s += x * x; }
#pragma unroll
    for (int off = 32; off; off >>= 1) s += __shfl_xor(s, off);
    if (lane == 0) nsq[row] = s;
}

#define BR 64
#define BC 128
#define BK 16
#define TR 4
#define TC 8

__global__ __launch_bounds__(256, 2)
void ge2e_main(const float* __restrict__ e, const float* __restrict__ cent,
               const float* __restrict__ nsq, const float* __restrict__ wp,
               const float* __restrict__ bp, float* __restrict__ partials) {
    __shared__ float As[BK][BR];
    __shared__ float Bs[BK][BC];
    __shared__ float diagLs[BR];
    __shared__ float red[16];

    const int tid = threadIdx.x;
    const int tx = tid & 15;
    const int ty = tid >> 4;
    const int blk = blockIdx.x;
    const int r0 = blk * BR;

    const float w = *wp;
    const float bb = *bp;

    float m_run[TR], s_run[TR];
#pragma unroll
    for (int i = 0; i < TR; ++i) { m_run[i] = NEG_INF; s_run[i] = 0.f; }

    const int a_row = tid >> 2;
    const int a_k   = (tid & 3) * 4;
    const int b_col = tid >> 1;
    const int b_k   = (tid & 1) * 8;

    for (int ct = 0; ct < N_SPK / BC; ++ct) {
        const int c0 = ct * BC;
        float acc[TR][TC];
#pragma unroll
        for (int i = 0; i < TR; ++i)
#pragma unroll
            for (int j = 0; j < TC; ++j) acc[i][j] = 0.f;

        for (int kk = 0; kk < D_EMB; kk += BK) {
            __syncthreads();
            {
                float4 av = *(const float4*)(e + (size_t)(r0 + a_row) * D_EMB + kk + a_k);
                As[a_k + 0][a_row] = av.x;
                As[a_k + 1][a_row] = av.y;
                As[a_k + 2][a_row] = av.z;
                As[a_k + 3][a_row] = av.w;
            }
            {
                const float* bp0 = cent + (size_t)(c0 + b_col) * D_EMB + kk + b_k;
                float4 bv0 = *(const float4*)(bp0);
                float4 bv1 = *(const float4*)(bp0 + 4);
                Bs[b_k + 0][b_col] = bv0.x;
                Bs[b_k + 1][b_col] = bv0.y;
                Bs[b_k + 2][b_col] = bv0.z;
                Bs[b_k + 3][b_col] = bv0.w;
                Bs[b_k + 4][b_col] = bv1.x;
                Bs[b_k + 5][b_col] = bv1.y;
                Bs[b_k + 6][b_col] = bv1.z;
                Bs[b_k + 7][b_col] = bv1.w;
            }
            __syncthreads();

#pragma unroll
            for (int k = 0; k < BK; ++k) {
                float4 a4 = *(const float4*)&As[k][ty * TR];
                float4 b4a = *(const float4*)&Bs[k][tx * TC];
                float4 b4b = *(const float4*)&Bs[k][tx * TC + 4];
                float av[TR] = {a4.x, a4.y, a4.z, a4.w};
                float bv[TC] = {b4a.x, b4a.y, b4a.z, b4a.w,
                                b4b.x, b4b.y, b4b.z, b4b.w};
#pragma unroll
                for (int i = 0; i < TR; ++i)
#pragma unroll
                    for (int j = 0; j < TC; ++j)
                        acc[i][j] = __builtin_fmaf(av[i], bv[j], acc[i][j]);
            }
        }

#pragma unroll
        for (int i = 0; i < TR; ++i) {
            const int grow = r0 + ty * TR + i;
            const int dcol = grow >> 5;
            float lv[TC];
#pragma unroll
            for (int j = 0; j < TC; ++j) {
                const int gcol = c0 + tx * TC + j;
                float v = acc[i][j];
                float lg;
                if (gcol == dcol) {
                    lg = __builtin_fmaf(w, __builtin_fmaf(32.0f, v,
                             (1.0f / 31.0f) * nsq[grow]), bb);
                    diagLs[ty * TR + i] = lg;
                } else {
                    lg = __builtin_fmaf(w, v, bb);
                }
                lv[j] = lg;
            }
            float mx = lv[0];
#pragma unroll
            for (int j = 1; j < TC; ++j) mx = fmaxf(mx, lv[j]);
#pragma unroll
            for (int off = 8; off; off >>= 1) mx = fmaxf(mx, __shfl_xor(mx, off));
            float ss = 0.f;
#pragma unroll
            for (int j = 0; j < TC; ++j) ss += __expf(lv[j] - mx);
#pragma unroll
            for (int off = 8; off; off >>= 1) ss += __shfl_xor(ss, off);
            float nm = fmaxf(m_run[i], mx);
            s_run[i] = s_run[i] * __expf(m_run[i] - nm) + ss * __expf(mx - nm);
            m_run[i] = nm;
        }
    }

    __syncthreads();
    if (tx == 0) {
        float part = 0.f;
#pragma unroll
        for (int i = 0; i < TR; ++i) {
            const int lr = ty * TR + i;
            part += m_run[i] + __logf(s_run[i]) - diagLs[lr];
        }
        red[ty] = part;
    }
    __syncthreads();
    if (tid == 0) {
        float t = 0.f;
#pragma unroll
        for (int i = 0; i < 16; ++i) t += red[i];
        partials[blk] = t;
    }
}

__global__ void reduce_kernel(const float* __restrict__ partials,
                              float* __restrict__ out) {
    __shared__ float red[4];
    int tid = threadIdx.x;
    float v = partials[tid] + partials[tid + 256];
#pragma unroll
    for (int off = 32; off; off >>= 1) v += __shfl_xor(v, off);
    if ((tid & 63) == 0) red[tid >> 6] = v;
    __syncthreads();
    if (tid == 0)
        out[0] = (red[0] + red[1] + red[2] + red[3]) * (1.0f / NROWS);
}

// ===========================================================================

extern "C" void kernel_launch(void* const* d_in, const int* in_sizes, int n_in,
                              void* d_out, int out_size, void* d_ws, size_t ws_size,
                              hipStream_t stream) {
    const float* e  = (const float*)d_in[0];   // [1024,32,512] f32
    const float* wp = (const float*)d_in[1];   // scalar
    const float* bp = (const float*)d_in[2];   // scalar
    float* out = (float*)d_out;

    // Fast-path workspace layout (bytes):
    //   sumf 2097152 | ssqA 131072 | dgl 131072 | active 131072 |
    //   pm16 4194304 (32768 rows x 16 x float2) | c2A 4096 | count 4 |
    //   blocksDone 4
    const size_t NEED_FAST = 6688776ull;

    if (ws_size >= NEED_FAST) {
        char* base = (char*)d_ws;
        float*  sumf       = (float*) (base);
        float*  ssqA       = (float*) (base + 2097152ull);
        float*  dgl        = (float*) (base + 2228224ull);
        int*    active     = (int*)   (base + 2359296ull);
        float2* pm16       = (float2*)(base + 2490368ull);
        float*  c2A        = (float*) (base + 6684672ull);
        int*    count      = (int*)   (base + 6688768ull);
        int*    blocksDone = (int*)   (base + 6688772ull);

        prep_kernel<<<N_SPK, 256, 0, stream>>>(e, sumf, ssqA, dgl, c2A,
                                               wp, bp, out, count, blocksDone);
        act2_kernel<<<1024, 64, 0, stream>>>(e, sumf, ssqA, dgl, c2A,
                                             wp, bp, count, active, pm16,
                                             blocksDone, out);
    } else {
        float* ws = (float*)d_ws;
        float* cent     = ws;
        float* nsq      = ws + 524288;
        float* partials = ws + 524288 + 32768;

        centroid_kernel<<<N_SPK * D_EMB / 256, 256, 0, stream>>>(e, cent);
        normsq_kernel<<<NROWS / 4, 256, 0, stream>>>(e, nsq);
        ge2e_main<<<NROWS / BR, 256, 0, stream>>>(e, cent, nsq, wp, bp, partials);
        reduce_kernel<<<1, 256, 0, stream>>>(partials, out);
    }
}

// Round 7
// 117.330 us; speedup vs baseline: 1.1158x; 1.1158x over previous
//
#include <hip/hip_runtime.h>

// Problem constants (fixed by the reference).
#define N_SPK 1024
#define M_UTT 32
#define D_EMB 512
#define NROWS (N_SPK * M_UTT)   // 32768

#define NEG_INF (-__builtin_inff())
#define MARGIN 25.0f   // skip row iff dgl - rowbound >= MARGIN (err < 1.4e-8/row)

using f32x4 = __attribute__((ext_vector_type(4))) float;

// ===========================================================================
// FAST PATH (round 17): prune-then-compute, 3 dispatches (reverted R16).
//
// R16 post-mortem: folding select into the active kernel REGRESSED 13us --
// all 1024 blocks replicated the 4KB c2A reduce (thundering-herd on 32 hot
// L2 lines) + a serial strip scan on every block's critical path + the
// finisher waits on all 1024 blocks.  Lesson: tiny one-hot-page kernels
// are cheaper as their own narrow dispatch than replicated grid-wide.
//
// R17 = R15 structure (best measured, 118.0us) + one prep micro-opt:
// the mi-loop is split into (1) load+accumulate all 8 rows, (2) the 8
// INDEPENDENT 6-deep shfl butterflies back-to-back so they pipeline
// instead of serializing one per row-load.  Per-value arithmetic order is
// untouched (same fma order, same butterfly tree) -> bit-exact.
//
// Active decomposition (R15): item = (slot, 64-speaker group), 64-thread
// blocks, 16 groups/slot, ~160-320 concurrent blocks.  The active phase
// scales with CONCURRENT BLOCK COUNT (R12: 10 blocks = 60us; R14: 64 ->
// 15us; R15: 320 -> ~6us) -- cross-CU memory-level parallelism.
// pm16[slot][g16] partials; done-counter crossing cnt*16 elects the
// merging block, which replays the R11 combine nesting -> absmax 0.0.
//
// Math unchanged from R10: dgl ~ 2641 +- 630 while every off-diag logit is
// bounded by |w|*||e||*max||c|| + b ~ 459 (Cauchy-Schwarz).  Rows with
// dgl - bound >= 25 nats contribute exactly-0 loss in the reference too.
// R11 kept: no init dispatch; c2A per-speaker array instead of atomicMax.
// ===========================================================================

// ---------------------------------------------------------------------------
// prep: one block per speaker n (32 rows x 512 dims).  Reads e ONCE.
//  - sumf[n*512+d] = sum_m e[n][m][d]      (fp32 speaker sum, 2 MB)
//  - ssqA[row]     = ||e_row||^2
//  - dgl[row]      = w*(e.sum + ||e||^2/31) + b   (exact fp32 diag logit)
//  - c2A[n]        = ||c_n||^2             (per-speaker, no atomics)
//  - block 0 zeroes out[0], *count, *doneCnt (replaces init dispatch)
// ---------------------------------------------------------------------------
__global__ __launch_bounds__(256)
void prep_kernel(const float* __restrict__ e,
                 float* __restrict__ sumf, float* __restrict__ ssqA,
                 float* __restrict__ dgl, float* __restrict__ c2A,
                 const float* __restrict__ wp, const float* __restrict__ bp,
                 float* __restrict__ out, int* __restrict__ count,
                 int* __restrict__ doneCnt) {
    __shared__ float csum[4][D_EMB];   // 8 KiB
    __shared__ float c2red[4];
    const int n = blockIdx.x;
    const int wv = threadIdx.x >> 6, l = threadIdx.x & 63;

    if (n == 0 && threadIdx.x == 0) { out[0] = 0.f; *count = 0; *doneCnt = 0; }

    float xs[8][8];     // retained row data (lane's 8 dims x 8 rows)
    float ssq[8];       // per-row ||e||^2 (wave-uniform after butterfly)
    float cacc[8];
#pragma unroll
    for (int j = 0; j < 8; ++j) cacc[j] = 0.f;

    // Phase 1: load all 8 rows + per-row local square-sums (no butterflies
    // on this critical path -- loads of all rows are independent).
#pragma unroll
    for (int mi = 0; mi < 8; ++mi) {
        const int m = mi * 4 + wv;
        const size_t row = (size_t)n * M_UTT + m;
        const float* p = e + row * D_EMB + l * 8;
        float4 x0 = *(const float4*)p;
        float4 x1 = *(const float4*)(p + 4);
        xs[mi][0] = x0.x; xs[mi][1] = x0.y; xs[mi][2] = x0.z; xs[mi][3] = x0.w;
        xs[mi][4] = x1.x; xs[mi][5] = x1.y; xs[mi][6] = x1.z; xs[mi][7] = x1.w;
        float sq = 0.f;
#pragma unroll
        for (int j = 0; j < 8; ++j) {
            float x = xs[mi][j];
            cacc[j] += x;
            sq = __builtin_fmaf(x, x, sq);
        }
        ssq[mi] = sq;   // lane-local partial; butterfly deferred
    }

    // Phase 2: 8 independent butterflies, back-to-back so the 6-deep shfl
    // chains pipeline across mi (identical tree per row -> bit-exact).
#pragma unroll
    for (int mi = 0; mi < 8; ++mi) {
        float sq = ssq[mi];
#pragma unroll
        for (int off = 32; off; off >>= 1) sq += __shfl_xor(sq, off);
        ssq[mi] = sq;
        if (l == 0) ssqA[(size_t)n * M_UTT + mi * 4 + wv] = sq;
    }

#pragma unroll
    for (int j = 0; j < 8; ++j) csum[wv][l * 8 + j] = cacc[j];
    __syncthreads();
    float c2acc = 0.f;
    for (int d = threadIdx.x; d < D_EMB; d += 256) {
        float s = csum[0][d] + csum[1][d] + csum[2][d] + csum[3][d];
        csum[0][d] = s;                               // full speaker sum
        sumf[(size_t)n * D_EMB + d] = s;
        float c = s * (1.0f / M_UTT);
        c2acc = __builtin_fmaf(c, c, c2acc);
    }
#pragma unroll
    for (int off = 32; off; off >>= 1) c2acc += __shfl_xor(c2acc, off);
    if (l == 0) c2red[wv] = c2acc;
    __syncthreads();   // csum[0] full sums + c2red visible
    if (threadIdx.x == 0)
        c2A[n] = (c2red[0] + c2red[1]) + (c2red[2] + c2red[3]);

    // Exact fp32 diag: dgl[row] = w*(e.sum + ssq/31) + b.
    float sv[8];
#pragma unroll
    for (int j = 0; j < 8; ++j) sv[j] = csum[0][l * 8 + j];
    const float w = wp[0], bb = bp[0];
#pragma unroll
    for (int mi = 0; mi < 8; ++mi) {
        float dg = 0.f;
#pragma unroll
        for (int j = 0; j < 8; ++j) dg = __builtin_fmaf(xs[mi][j], sv[j], dg);
#pragma unroll
        for (int off = 32; off; off >>= 1) dg += __shfl_xor(dg, off);
        if (l == 0) {
            const size_t row = (size_t)n * M_UTT + mi * 4 + wv;
            dgl[row] = __builtin_fmaf(w, dg + ssq[mi] * (1.0f / 31.0f), bb);
        }
    }
}

// ---------------------------------------------------------------------------
// select: one thread per row.  Each block first max-reduces c2A (4 KB,
// L2-hot) to Cmax^2 — exact same max the old atomicMax produced (fmaxf is
// rounding-free, order-independent).  Row survives iff
// dgl - (|w|*||e||*Cmax + b) < MARGIN.  Survivors appended to active[]
// (device atomic; ~10-20 appends total).
// ---------------------------------------------------------------------------
__global__ __launch_bounds__(256)
void select_kernel(const float* __restrict__ ssqA, const float* __restrict__ dgl,
                   const float* __restrict__ c2A,
                   const float* __restrict__ wp, const float* __restrict__ bp,
                   int* __restrict__ count, int* __restrict__ active) {
    __shared__ float red[4];
    float m = 0.f;   // c2 > 0 always
#pragma unroll
    for (int i = 0; i < 4; ++i)
        m = fmaxf(m, c2A[threadIdx.x + i * 256]);
#pragma unroll
    for (int off = 32; off; off >>= 1) m = fmaxf(m, __shfl_xor(m, off));
    if ((threadIdx.x & 63) == 0) red[threadIdx.x >> 6] = m;
    __syncthreads();
    const float c2 = fmaxf(fmaxf(red[0], red[1]), fmaxf(red[2], red[3]));
    const float Cmax = __builtin_sqrtf(c2);

    const int row = blockIdx.x * 256 + threadIdx.x;
    const float bound = __builtin_fmaf(
        __builtin_fabsf(wp[0]) * __builtin_sqrtf(ssqA[row]), Cmax, bp[0]);
    if (dgl[row] - bound < MARGIN) {
        int slot = atomicAdd(count, 1);
        active[slot] = row;
    }
}

// ---------------------------------------------------------------------------
// active (fused merge): item = (slot, 64-speaker group g16).  ONE WAVE per
// block; lane t computes speaker j = g16*64 + t with the identical dot
// chain and the identical 64-lane butterfly as R11's wave (chunk=g16>>2,
// wv=g16&3).  Lane 0 release-stores the (max,sumexp) partial to
// pm16[slot*16+g16] and the block counts its items into doneCnt; the
// unique block crossing cnt*16 merges every slot with the identical old
// nesting (per-chunk 4-group combine, then 4-chunk combine) -> bit-exact.
// ---------------------------------------------------------------------------
__global__ __launch_bounds__(64)
void active_kernel(const float* __restrict__ e, const float* __restrict__ sumf,
                   const float* __restrict__ dgl,
                   const int* __restrict__ count, const int* __restrict__ active,
                   const float* __restrict__ wp, const float* __restrict__ bp,
                   float2* __restrict__ pm16, int* __restrict__ doneCnt,
                   float* __restrict__ out) {
    __shared__ float er[D_EMB];
    __shared__ int lastFlag;
    const int tid = threadIdx.x;   // 0..63
    const int cnt = *count;
    if (cnt == 0) return;          // out already 0 from prep
    const float w = wp[0], bb = bp[0];

    const int g16 = blockIdx.x & 15;          // 64-speaker group
    const int slot0 = blockIdx.x >> 4;
    const int gstride = gridDim.x >> 4;       // 64

    if (tid == 0) lastFlag = 0;
    int myItems = 0;

    for (int slot = slot0; slot < cnt; slot += gstride) {
        const int row = active[slot];
        __syncthreads();   // protect er (and lastFlag init, 1st iter)
#pragma unroll
        for (int i = 0; i < 8; ++i)
            er[tid + i * 64] = e[(size_t)row * D_EMB + tid + i * 64];
        __syncthreads();

        const int j = g16 * 64 + tid;         // speaker (column) index
        const float* sp = sumf + (size_t)j * D_EMB;
        float d0 = 0.f, d1 = 0.f, d2 = 0.f, d3 = 0.f;
        for (int k = 0; k < D_EMB; k += 4) {
            float4 s4 = *(const float4*)(sp + k);
            d0 = __builtin_fmaf(er[k + 0], s4.x, d0);
            d1 = __builtin_fmaf(er[k + 1], s4.y, d1);
            d2 = __builtin_fmaf(er[k + 2], s4.z, d2);
            d3 = __builtin_fmaf(er[k + 3], s4.w, d3);
        }
        const float dot = (d0 + d1) + (d2 + d3);
        float lg = __builtin_fmaf(w, dot * (1.0f / M_UTT), bb);
        if (j == (row >> 5)) lg = dgl[row];   // exact diag substitution

        float mx = lg;
#pragma unroll
        for (int off = 32; off; off >>= 1) mx = fmaxf(mx, __shfl_xor(mx, off));
        float ss = __expf(lg - mx);
#pragma unroll
        for (int off = 32; off; off >>= 1) ss += __shfl_xor(ss, off);
        if (tid == 0) {
            float2 v; v.x = mx; v.y = ss;
            __hip_atomic_store((unsigned long long*)&pm16[slot * 16 + g16],
                               __builtin_bit_cast(unsigned long long, v),
                               __ATOMIC_RELAXED, __HIP_MEMORY_SCOPE_AGENT);
        }
        ++myItems;
    }

    __syncthreads();
    if (tid == 0 && myItems > 0) {
        int old = __hip_atomic_fetch_add(doneCnt, myItems,
                                         __ATOMIC_ACQ_REL,
                                         __HIP_MEMORY_SCOPE_AGENT);
        if (old + myItems == cnt * 16) lastFlag = 1;   // unique crossing block
    }
    __syncthreads();

    if (lastFlag) {
        // Merge ALL slots with the identical old nesting:
        //   per chunk c: combine groups 4c..4c+3 (old red2[c][0..3] order),
        //   then the old merge_kernel 4-chunk combine.
        for (int slot = tid; slot < cnt; slot += 64) {
            float2 pm[4];
#pragma unroll
            for (int c = 0; c < 4; ++c) {
                float2 r0, r1, r2, r3;
                unsigned long long b0 = __hip_atomic_load(
                    (unsigned long long*)&pm16[slot * 16 + 4 * c + 0],
                    __ATOMIC_RELAXED, __HIP_MEMORY_SCOPE_AGENT);
                unsigned long long b1 = __hip_atomic_load(
                    (unsigned long long*)&pm16[slot * 16 + 4 * c + 1],
                    __ATOMIC_RELAXED, __HIP_MEMORY_SCOPE_AGENT);
                unsigned long long b2 = __hip_atomic_load(
                    (unsigned long long*)&pm16[slot * 16 + 4 * c + 2],
                    __ATOMIC_RELAXED, __HIP_MEMORY_SCOPE_AGENT);
                unsigned long long b3 = __hip_atomic_load(
                    (unsigned long long*)&pm16[slot * 16 + 4 * c + 3],
                    __ATOMIC_RELAXED, __HIP_MEMORY_SCOPE_AGENT);
                r0 = __builtin_bit_cast(float2, b0);
                r1 = __builtin_bit_cast(float2, b1);
                r2 = __builtin_bit_cast(float2, b2);
                r3 = __builtin_bit_cast(float2, b3);
                float M = fmaxf(fmaxf(r0.x, r1.x), fmaxf(r2.x, r3.x));
                float S = r0.y * __expf(r0.x - M)
                        + r1.y * __expf(r1.x - M)
                        + r2.y * __expf(r2.x - M)
                        + r3.y * __expf(r3.x - M);
                pm[c].x = M; pm[c].y = S;
            }
            float M = fmaxf(fmaxf(pm[0].x, pm[1].x), fmaxf(pm[2].x, pm[3].x));
            float S = pm[0].y * __expf(pm[0].x - M) + pm[1].y * __expf(pm[1].x - M)
                    + pm[2].y * __expf(pm[2].x - M) + pm[3].y * __expf(pm[3].x - M);
            float loss = M + __logf(S) - dgl[active[slot]];
            atomicAdd(out, loss * (1.0f / NROWS));
        }
    }
}

// ===========================================================================
// FALLBACK PATH (round-1 fp32 vector kernels) — used if ws_size is too small.
// ===========================================================================

__global__ void centroid_kernel(const float* __restrict__ e,
                                float* __restrict__ cent) {
    int gid = blockIdx.x * 256 + threadIdx.x;
    int n = gid >> 9;
    int d = gid & 511;
    const float* p = e + ((size_t)n * M_UTT) * D_EMB + d;
    float s = 0.f;
#pragma unroll
    for (int m = 0; m < M_UTT; ++m) s += p[(size_t)m * D_EMB];
    cent[gid] = s * (1.0f / M_UTT);
}

__global__ void normsq_kernel(const float* __restrict__ e,
                              float* __restrict__ nsq) {
    int wv = threadIdx.x >> 6;
    int lane = threadIdx.x & 63;
    int row = blockIdx.x * 4 + wv;
    const float* p = e + (size_t)row * D_EMB + lane;
    float s = 0.f;
#pragma unroll
    for (int j = 0; j < 8; ++j) { float x = p[j * 64]; s += x * x; }
#pragma unroll
    for (int off = 32; off; off >>= 1) s += __shfl_xor(s, off);
    if (lane == 0) nsq[row] = s;
}

#define BR 64
#define BC 128
#define BK 16
#define TR 4
#define TC 8

__global__ __launch_bounds__(256, 2)
void ge2e_main(const float* __restrict__ e, const float* __restrict__ cent,
               const float* __restrict__ nsq, const float* __restrict__ wp,
               const float* __restrict__ bp, float* __restrict__ partials) {
    __shared__ float As[BK][BR];
    __shared__ float Bs[BK][BC];
    __shared__ float diagLs[BR];
    __shared__ float red[16];

    const int tid = threadIdx.x;
    const int tx = tid & 15;
    const int ty = tid >> 4;
    const int blk = blockIdx.x;
    const int r0 = blk * BR;

    const float w = *wp;
    const float bb = *bp;

    float m_run[TR], s_run[TR];
#pragma unroll
    for (int i = 0; i < TR; ++i) { m_run[i] = NEG_INF; s_run[i] = 0.f; }

    const int a_row = tid >> 2;
    const int a_k   = (tid & 3) * 4;
    const int b_col = tid >> 1;
    const int b_k   = (tid & 1) * 8;

    for (int ct = 0; ct < N_SPK / BC; ++ct) {
        const int c0 = ct * BC;
        float acc[TR][TC];
#pragma unroll
        for (int i = 0; i < TR; ++i)
#pragma unroll
            for (int j = 0; j < TC; ++j) acc[i][j] = 0.f;

        for (int kk = 0; kk < D_EMB; kk += BK) {
            __syncthreads();
            {
                float4 av = *(const float4*)(e + (size_t)(r0 + a_row) * D_EMB + kk + a_k);
                As[a_k + 0][a_row] = av.x;
                As[a_k + 1][a_row] = av.y;
                As[a_k + 2][a_row] = av.z;
                As[a_k + 3][a_row] = av.w;
            }
            {
                const float* bp0 = cent + (size_t)(c0 + b_col) * D_EMB + kk + b_k;
                float4 bv0 = *(const float4*)(bp0);
                float4 bv1 = *(const float4*)(bp0 + 4);
                Bs[b_k + 0][b_col] = bv0.x;
                Bs[b_k + 1][b_col] = bv0.y;
                Bs[b_k + 2][b_col] = bv0.z;
                Bs[b_k + 3][b_col] = bv0.w;
                Bs[b_k + 4][b_col] = bv1.x;
                Bs[b_k + 5][b_col] = bv1.y;
                Bs[b_k + 6][b_col] = bv1.z;
                Bs[b_k + 7][b_col] = bv1.w;
            }
            __syncthreads();

#pragma unroll
            for (int k = 0; k < BK; ++k) {
                float4 a4 = *(const float4*)&As[k][ty * TR];
                float4 b4a = *(const float4*)&Bs[k][tx * TC];
                float4 b4b = *(const float4*)&Bs[k][tx * TC + 4];
                float av[TR] = {a4.x, a4.y, a4.z, a4.w};
                float bv[TC] = {b4a.x, b4a.y, b4a.z, b4a.w,
                                b4b.x, b4b.y, b4b.z, b4b.w};
#pragma unroll
                for (int i = 0; i < TR; ++i)
#pragma unroll
                    for (int j = 0; j < TC; ++j)
                        acc[i][j] = __builtin_fmaf(av[i], bv[j], acc[i][j]);
            }
        }

#pragma unroll
        for (int i = 0; i < TR; ++i) {
            const int grow = r0 + ty * TR + i;
            const int dcol = grow >> 5;
            float lv[TC];
#pragma unroll
            for (int j = 0; j < TC; ++j) {
                const int gcol = c0 + tx * TC + j;
                float v = acc[i][j];
                float lg;
                if (gcol == dcol) {
                    lg = __builtin_fmaf(w, __builtin_fmaf(32.0f, v,
                             (1.0f / 31.0f) * nsq[grow]), bb);
                    diagLs[ty * TR + i] = lg;
                } else {
                    lg = __builtin_fmaf(w, v, bb);
                }
                lv[j] = lg;
            }
            float mx = lv[0];
#pragma unroll
            for (int j = 1; j < TC; ++j) mx = fmaxf(mx, lv[j]);
#pragma unroll
            for (int off = 8; off; off >>= 1) mx = fmaxf(mx, __shfl_xor(mx, off));
            float ss = 0.f;
#pragma unroll
            for (int j = 0; j < TC; ++j) ss += __expf(lv[j] - mx);
#pragma unroll
            for (int off = 8; off; off >>= 1) ss += __shfl_xor(ss, off);
            float nm = fmaxf(m_run[i], mx);
            s_run[i] = s_run[i] * __expf(m_run[i] - nm) + ss * __expf(mx - nm);
            m_run[i] = nm;
        }
    }

    __syncthreads();
    if (tx == 0) {
        float part = 0.f;
#pragma unroll
        for (int i = 0; i < TR; ++i) {
            const int lr = ty * TR + i;
            part += m_run[i] + __logf(s_run[i]) - diagLs[lr];
        }
        red[ty] = part;
    }
    __syncthreads();
    if (tid == 0) {
        float t = 0.f;
#pragma unroll
        for (int i = 0; i < 16; ++i) t += red[i];
        partials[blk] = t;
    }
}

__global__ void reduce_kernel(const float* __restrict__ partials,
                              float* __restrict__ out) {
    __shared__ float red[4];
    int tid = threadIdx.x;
    float v = partials[tid] + partials[tid + 256];
#pragma unroll
    for (int off = 32; off; off >>= 1) v += __shfl_xor(v, off);
    if ((tid & 63) == 0) red[tid >> 6] = v;
    __syncthreads();
    if (tid == 0)
        out[0] = (red[0] + red[1] + red[2] + red[3]) * (1.0f / NROWS);
}

// ===========================================================================

extern "C" void kernel_launch(void* const* d_in, const int* in_sizes, int n_in,
                              void* d_out, int out_size, void* d_ws, size_t ws_size,
                              hipStream_t stream) {
    const float* e  = (const float*)d_in[0];   // [1024,32,512] f32
    const float* wp = (const float*)d_in[1];   // scalar
    const float* bp = (const float*)d_in[2];   // scalar
    float* out = (float*)d_out;

    // Fast-path workspace layout (bytes):
    //   sumf 2097152 | ssqA 131072 | dgl 131072 | active 131072 |
    //   pm16 4194304 (32768 slots x 16 x float2) | c2A 4096 | count 4 |
    //   doneCnt 4
    const size_t NEED_FAST = 6688776ull;

    if (ws_size >= NEED_FAST) {
        char* base = (char*)d_ws;
        float*  sumf    = (float*) (base);
        float*  ssqA    = (float*) (base + 2097152ull);
        float*  dgl     = (float*) (base + 2228224ull);
        int*    active  = (int*)   (base + 2359296ull);
        float2* pm16    = (float2*)(base + 2490368ull);
        float*  c2A     = (float*) (base + 6684672ull);
        int*    count   = (int*)   (base + 6688768ull);
        int*    doneCnt = (int*)   (base + 6688772ull);

        prep_kernel<<<N_SPK, 256, 0, stream>>>(e, sumf, ssqA, dgl, c2A,
                                               wp, bp, out, count, doneCnt);
        select_kernel<<<NROWS / 256, 256, 0, stream>>>(ssqA, dgl, c2A,
                                                       wp, bp, count, active);
        active_kernel<<<1024, 64, 0, stream>>>(e, sumf, dgl, count, active,
                                               wp, bp, pm16, doneCnt, out);
    } else {
        float* ws = (float*)d_ws;
        float* cent     = ws;
        float* nsq      = ws + 524288;
        float* partials = ws + 524288 + 32768;

        centroid_kernel<<<N_SPK * D_EMB / 256, 256, 0, stream>>>(e, cent);
        normsq_kernel<<<NROWS / 4, 256, 0, stream>>>(e, nsq);
        ge2e_main<<<NROWS / BR, 256, 0, stream>>>(e, cent, nsq, wp, bp, partials);
        reduce_kernel<<<1, 256, 0, stream>>>(partials, out);
    }
}